// Round 6
// baseline (191.874 us; speedup 1.0000x reference)
//
#include <hip/hip_runtime.h>
#include <cstddef>

// Sizes (fixed per reference): B=8192, D=784, H=256, E=32, K=512
#define NB 8192
#define ND 784
#define NH 256
#define NE 32
#define NK 512
#define ALPHA_F 1000.0f

typedef _Float16 h8 __attribute__((ext_vector_type(8)));
typedef float f32x4 __attribute__((ext_vector_type(4)));

// ---------------------------------------------------------------------------
// Merged weight split+transpose: W [K][N] fp32 -> WT hi/lo [N][K] fp16.
// blocks 0..NH-1: W1 (K=ND); blocks NH..NH+ND-1: W4 (K=NH).
// w ~= hi + lo*2^-11; fp16 products exact in fp32 MFMA accumulator.
// ---------------------------------------------------------------------------
__global__ __launch_bounds__(256)
void splitw2_kernel(const float* __restrict__ W1, _Float16* __restrict__ w1thi,
                    _Float16* __restrict__ w1tlo,
                    const float* __restrict__ W4, _Float16* __restrict__ w4thi,
                    _Float16* __restrict__ w4tlo) {
    const int b = blockIdx.x;
    const float* W; _Float16 *hi, *lo; int K, N, n;
    if (b < NH) { W = W1; hi = w1thi; lo = w1tlo; K = ND; N = NH; n = b; }
    else        { W = W4; hi = w4thi; lo = w4tlo; K = NH; N = ND; n = b - NH; }
    for (int k = threadIdx.x; k < K; k += 256) {
        float w = W[(size_t)k * N + n];
        _Float16 hh = (_Float16)w;
        float r = w - (float)hh;
        hi[(size_t)n * K + k] = hh;
        lo[(size_t)n * K + k] = (_Float16)(r * 2048.0f);
    }
}

// ---------------------------------------------------------------------------
// MFMA split-fp16 GEMM v2: C[M,N] = op(A[M,K] @ W[K,N] + bias).
// W given TRANSPOSED as hi/lo planes [N][K].  A either fp32 [M][K]
// (SPLITA: hi/lo conversion fused into staging — kills the split_x pass)
// or as hi/lo fp16 planes.
// Block tile BM x 64, BK=32.  BM=64 -> 128 thr (2 waves), BM=128 -> 256 thr.
// Wave tile 64x32 = 4x2 of 16x16x32 MFMA: 12 ds_read_b128 feed
// TERMS*8 MFMAs per step (2x the FLOP/LDS-byte of the 2x2 layout).
// TERMS=4: hh + (hi*lo + lo*hi) + ll (fp32-class, encoder);
// TERMS=3: drop ll (decoder).  K ragged: 16-elem chunks zero-filled.
// LDS rows padded to 40 fp16 (80 B).
// ---------------------------------------------------------------------------
template<int TERMS, bool RELU, bool SPLITA, int BM>
__global__ __launch_bounds__(BM == 64 ? 128 : 256)
void mfma_gemm2(const float* __restrict__ Af32,
                const _Float16* __restrict__ Ahi_g,
                const _Float16* __restrict__ Alo_g,
                const _Float16* __restrict__ WThi,
                const _Float16* __restrict__ WTlo,
                const float* __restrict__ bias, float* __restrict__ C,
                int N, int K, int KS) {
    constexpr int T   = (BM == 64) ? 128 : 256;
    constexpr int BC  = 2048 / T;     // B elems/thread/plane: 16 or 8
    constexpr int BTR = 32 / BC;      // threads per B row: 2 or 4
    constexpr int BH8 = BC / 8;       // h8 chunks: 2 or 1

    __shared__ _Float16 sAhi[BM * 40];
    __shared__ _Float16 sAlo[BM * 40];
    __shared__ _Float16 sBhi[64 * 40];
    __shared__ _Float16 sBlo[64 * 40];

    const int tid = threadIdx.x;
    const int bm  = blockIdx.x * BM;
    const int bn  = blockIdx.y * 64;

    // A staging: 16 k-elems per thread
    const int arow = tid >> 1;
    const int ak   = (tid & 1) * 16;
    // B staging
    const int brow = tid / BTR;
    const int bk   = (tid % BTR) * BC;

    const float*    pA32 = SPLITA ? Af32 + (size_t)(bm + arow) * K : nullptr;
    const _Float16* pAhi = SPLITA ? nullptr : Ahi_g + (size_t)(bm + arow) * K;
    const _Float16* pAlo = SPLITA ? nullptr : Alo_g + (size_t)(bm + arow) * K;
    int brow_g = bn + brow; if (brow_g > N - 1) brow_g = N - 1;  // N-edge tile
    const _Float16* pBhi = WThi + (size_t)brow_g * K;
    const _Float16* pBlo = WTlo + (size_t)brow_g * K;

    h8 ra_hi[2], ra_lo[2], rb_hi[2], rb_lo[2];

    auto loadA = [&](int k) {
        if (k < K) {  // chunk of 16 fully in-bounds (K % 16 == 0)
            if (SPLITA) {
                #pragma unroll
                for (int c = 0; c < 2; ++c) {
                    f32x4 v0 = ((const f32x4*)(pA32 + k + c * 8))[0];
                    f32x4 v1 = ((const f32x4*)(pA32 + k + c * 8))[1];
                    float vv[8] = {v0[0], v0[1], v0[2], v0[3],
                                   v1[0], v1[1], v1[2], v1[3]};
                    #pragma unroll
                    for (int j = 0; j < 8; ++j) {
                        _Float16 hh = (_Float16)vv[j];
                        ra_hi[c][j] = hh;
                        ra_lo[c][j] = (_Float16)((vv[j] - (float)hh) * 2048.0f);
                    }
                }
            } else {
                ra_hi[0] = *(const h8*)(pAhi + k);
                ra_hi[1] = *(const h8*)(pAhi + k + 8);
                ra_lo[0] = *(const h8*)(pAlo + k);
                ra_lo[1] = *(const h8*)(pAlo + k + 8);
            }
        } else {
            ra_hi[0] = ra_hi[1] = ra_lo[0] = ra_lo[1] = (h8){};
        }
    };
    auto loadB = [&](int k) {
        if (k < K) {
            #pragma unroll
            for (int c = 0; c < BH8; ++c) {
                rb_hi[c] = *(const h8*)(pBhi + k + c * 8);
                rb_lo[c] = *(const h8*)(pBlo + k + c * 8);
            }
        } else {
            #pragma unroll
            for (int c = 0; c < BH8; ++c) { rb_hi[c] = (h8){}; rb_lo[c] = (h8){}; }
        }
    };

    loadA(ak);
    loadB(bk);

    // wave mapping: wave tile 64x32
    const int lane = tid & 63;
    const int wv   = tid >> 6;
    const int wm   = (BM == 128) ? (wv >> 1) * 64 : 0;
    const int wn   = (BM == 128) ? (wv & 1) * 32 : wv * 32;
    const int li   = lane & 15;
    const int kq   = (lane >> 4) * 8;

    f32x4 acc0[4][2] = {};
    f32x4 acc1[4][2] = {};
    f32x4 acc2[4][2] = {};

    const int soffA = arow * 40 + ak;
    const int soffB = brow * 40 + bk;

    for (int s = 0; s < KS; ++s) {
        *(h8*)&sAhi[soffA]     = ra_hi[0];
        *(h8*)&sAhi[soffA + 8] = ra_hi[1];
        *(h8*)&sAlo[soffA]     = ra_lo[0];
        *(h8*)&sAlo[soffA + 8] = ra_lo[1];
        #pragma unroll
        for (int c = 0; c < BH8; ++c) {
            *(h8*)&sBhi[soffB + c * 8] = rb_hi[c];
            *(h8*)&sBlo[soffB + c * 8] = rb_lo[c];
        }
        __syncthreads();

        if (s + 1 < KS) {
            loadA((s + 1) * 32 + ak);
            loadB((s + 1) * 32 + bk);
        }

        h8 fahi[4], falo[4], fbhi[2], fblo[2];
        #pragma unroll
        for (int mt = 0; mt < 4; ++mt) {
            const int ao = (wm + mt * 16 + li) * 40 + kq;
            fahi[mt] = *(const h8*)&sAhi[ao];
            falo[mt] = *(const h8*)&sAlo[ao];
        }
        #pragma unroll
        for (int nt = 0; nt < 2; ++nt) {
            const int bo = (wn + nt * 16 + li) * 40 + kq;
            fbhi[nt] = *(const h8*)&sBhi[bo];
            fblo[nt] = *(const h8*)&sBlo[bo];
        }
        #pragma unroll
        for (int mt = 0; mt < 4; ++mt)
            #pragma unroll
            for (int nt = 0; nt < 2; ++nt) {
                acc0[mt][nt] = __builtin_amdgcn_mfma_f32_16x16x32_f16(
                    fahi[mt], fbhi[nt], acc0[mt][nt], 0, 0, 0);
                acc1[mt][nt] = __builtin_amdgcn_mfma_f32_16x16x32_f16(
                    fahi[mt], fblo[nt], acc1[mt][nt], 0, 0, 0);
                acc1[mt][nt] = __builtin_amdgcn_mfma_f32_16x16x32_f16(
                    falo[mt], fbhi[nt], acc1[mt][nt], 0, 0, 0);
                if (TERMS == 4)
                    acc2[mt][nt] = __builtin_amdgcn_mfma_f32_16x16x32_f16(
                        falo[mt], fblo[nt], acc2[mt][nt], 0, 0, 0);
            }
        __syncthreads();
    }

    const float c1 = 1.0f / 2048.0f;
    const float c2 = c1 * c1;
    const int quad = lane >> 4;
    #pragma unroll
    for (int nt = 0; nt < 2; ++nt) {
        const int n = bn + wn + nt * 16 + li;
        if (n < N) {
            const float bv = bias[n];
            #pragma unroll
            for (int mt = 0; mt < 4; ++mt) {
                #pragma unroll
                for (int r = 0; r < 4; ++r) {
                    const int m = bm + wm + mt * 16 + quad * 4 + r;
                    float v = acc0[mt][nt][r] + c1 * acc1[mt][nt][r];
                    if (TERMS == 4) v += c2 * acc2[mt][nt][r];
                    v += bv;
                    if (RELU) v = fmaxf(v, 0.f);
                    C[(size_t)m * N + n] = v;
                }
            }
        }
    }
}

// ---------------------------------------------------------------------------
// Fused: emb[B,32] = h@W2+b2 (fp32, precision-critical);
//        h2 = relu(emb@W3+b3) emitted as fp16 hi/lo planes for gemm4.
// Block = 16 rows, 256 threads, 512 blocks.
// ---------------------------------------------------------------------------
__global__ __launch_bounds__(256)
void mid_kernel(const float* __restrict__ h, const float* __restrict__ W2,
                const float* __restrict__ b2, const float* __restrict__ W3,
                const float* __restrict__ b3, float* __restrict__ emb,
                _Float16* __restrict__ h2hi, _Float16* __restrict__ h2lo) {
    __shared__ float es[16][32];
    const int tid = threadIdx.x;
    const int r0  = blockIdx.x * 16;

    #pragma unroll
    for (int half = 0; half < 2; ++half) {
        const int o   = tid + half * 256;
        const int row = o >> 5;
        const int col = o & 31;
        const float* hrow = h + (size_t)(r0 + row) * NH;
        float acc0 = 0.f, acc1 = 0.f;
        #pragma unroll 4
        for (int k = 0; k < NH; k += 4) {
            float4 hv = *(const float4*)(hrow + k);
            acc0 = fmaf(hv.x, W2[(k + 0) * NE + col], acc0);
            acc1 = fmaf(hv.y, W2[(k + 1) * NE + col], acc1);
            acc0 = fmaf(hv.z, W2[(k + 2) * NE + col], acc0);
            acc1 = fmaf(hv.w, W2[(k + 3) * NE + col], acc1);
        }
        float v = acc0 + acc1 + b2[col];
        es[row][col] = v;
        emb[(size_t)r0 * NE + o] = v;
    }
    __syncthreads();

    const int col = tid;
    float acc[16];
    #pragma unroll
    for (int r = 0; r < 16; ++r) acc[r] = 0.f;
    #pragma unroll
    for (int k = 0; k < NE; ++k) {
        float w = W3[k * NH + col];
        #pragma unroll
        for (int r = 0; r < 16; ++r) acc[r] = fmaf(es[r][k], w, acc[r]);
    }
    const float bb = b3[col];
    #pragma unroll
    for (int r = 0; r < 16; ++r) {
        float v = acc[r] + bb;
        v = v > 0.f ? v : 0.f;
        _Float16 hh = (_Float16)v;
        float rr = v - (float)hh;
        h2hi[(size_t)(r0 + r) * NH + col] = hh;
        h2lo[(size_t)(r0 + r) * NH + col] = (_Float16)(rr * 2048.0f);
    }
}

// ---------------------------------------------------------------------------
// Distances + stable softmin (v3, verified).
// 1024 blocks x 512 threads. Thread owns ONE cluster (tid) for 8 rows.
// Row reductions via padded LDS transpose + one 6-step shuffle.
// ---------------------------------------------------------------------------
__global__ __launch_bounds__(512, 4)
void dist_kernel(const float* __restrict__ emb, const float* __restrict__ reps,
                 float* __restrict__ dist, float* __restrict__ wout) {
    __shared__ float es[8][32];
    __shared__ float tr[8][520];
    __shared__ float rmin[8];
    __shared__ float rinv[8];

    const int tid = threadIdx.x;      // == cluster id
    const int r0  = blockIdx.x * 8;

    if (tid < 256) es[tid >> 5][tid & 31] = emb[(size_t)r0 * NE + tid];

    const float* rp = reps + (size_t)tid * NE;
    f32x4 rv[8];
    #pragma unroll
    for (int e4 = 0; e4 < 8; ++e4) rv[e4] = ((const f32x4*)rp)[e4];
    __syncthreads();

    float d[8];
    #pragma unroll
    for (int r = 0; r < 8; ++r) {
        float a = 0.f;
        #pragma unroll
        for (int e4 = 0; e4 < 8; ++e4) {
            f32x4 ev = *(const f32x4*)&es[r][e4 * 4];
            #pragma unroll
            for (int j = 0; j < 4; ++j) {
                float t = ev[j] - rv[e4][j];
                a = fmaf(t, t, a);
            }
        }
        d[r] = a;
    }

    const int lane = tid & 63;
    const int wv   = tid >> 6;

    #pragma unroll
    for (int r = 0; r < 8; ++r) tr[r][tid] = d[r];
    __syncthreads();
    {
        f32x4 a = *(const f32x4*)&tr[wv][lane * 8];
        f32x4 b = *(const f32x4*)&tr[wv][lane * 8 + 4];
        float m = fminf(fminf(fminf(a[0], a[1]), fminf(a[2], a[3])),
                        fminf(fminf(b[0], b[1]), fminf(b[2], b[3])));
        #pragma unroll
        for (int off = 32; off > 0; off >>= 1)
            m = fminf(m, __shfl_xor(m, off, 64));
        if (lane == 0) rmin[wv] = m;
    }
    __syncthreads();

    float e[8];
    #pragma unroll
    for (int r = 0; r < 8; ++r) {
        e[r] = expf(-ALPHA_F * (d[r] - rmin[r]));
        tr[r][tid] = e[r];
    }
    __syncthreads();
    {
        f32x4 a = *(const f32x4*)&tr[wv][lane * 8];
        f32x4 b = *(const f32x4*)&tr[wv][lane * 8 + 4];
        float s = ((a[0] + a[1]) + (a[2] + a[3])) +
                  ((b[0] + b[1]) + (b[2] + b[3]));
        #pragma unroll
        for (int off = 32; off > 0; off >>= 1)
            s += __shfl_xor(s, off, 64);
        if (lane == 0) rinv[wv] = 1.0f / s;
    }
    __syncthreads();

    #pragma unroll
    for (int r = 0; r < 8; ++r) {
        const size_t row = (size_t)(r0 + r);
        dist[row * NK + tid] = d[r];
        wout[row * NK + tid] = d[r] * (e[r] * rinv[r]);
    }
}

// ---------------------------------------------------------------------------
extern "C" void kernel_launch(void* const* d_in, const int* in_sizes, int n_in,
                              void* d_out, int out_size, void* d_ws, size_t ws_size,
                              hipStream_t stream) {
    const float* x    = (const float*)d_in[0];
    const float* reps = (const float*)d_in[1];
    const float* W1   = (const float*)d_in[2];
    const float* b1   = (const float*)d_in[3];
    const float* W2   = (const float*)d_in[4];
    const float* b2   = (const float*)d_in[5];
    const float* W3   = (const float*)d_in[6];
    const float* b3   = (const float*)d_in[7];
    const float* W4   = (const float*)d_in[8];
    const float* b4   = (const float*)d_in[9];

    float* out   = (float*)d_out;
    float* wout  = out;                                          // [8192,512]
    float* dist  = out + (size_t)NB * NK;                        // [8192,512]
    float* recon = out + (size_t)2 * NB * NK;                    // [8192,784]
    float* emb   = out + (size_t)2 * NB * NK + (size_t)NB * ND;  // [8192,32]

    // Scratch aliased into output regions not yet written at time of use:
    //  dist region (16 MiB): h fp32 (8 MiB) + h2 hi/lo planes (4+4 MiB);
    //    all dead before dist_kernel overwrites.
    //  wout region: W1T/W4T hi/lo planes (1.6 MiB); dead before dist_kernel.
    float*    h     = dist;
    _Float16* h2hi  = (_Float16*)(dist + (size_t)NB * NH);
    _Float16* h2lo  = h2hi + (size_t)NB * NH;
    _Float16* w1thi = (_Float16*)wout;
    _Float16* w1tlo = w1thi + (size_t)NH * ND;
    _Float16* w4thi = w1tlo + (size_t)NH * ND;
    _Float16* w4tlo = w4thi + (size_t)ND * NH;

    // 0) weight split+transpose (one launch for both W1 and W4)
    splitw2_kernel<<<NH + ND, 256, 0, stream>>>(W1, w1thi, w1tlo,
                                                W4, w4thi, w4tlo);

    // 1) h = relu(x @ W1 + b1)   M=8192 N=256 K=784, BM=64, KS=25
    //    (x fp32 read directly; hi/lo split fused into staging)
    mfma_gemm2<4, true, true, 64><<<dim3(128, 4), 128, 0, stream>>>(
        x, nullptr, nullptr, w1thi, w1tlo, b1, h, NH, ND, 25);

    // 2) emb + h2 (fp16 planes)
    mid_kernel<<<NB / 16, 256, 0, stream>>>(h, W2, b2, W3, b3, emb, h2hi, h2lo);

    // 3) recon = h2 @ W4 + b4    M=8192 N=784 K=256, BM=128, KS=8
    mfma_gemm2<3, false, false, 128><<<dim3(64, 13), 256, 0, stream>>>(
        nullptr, h2hi, h2lo, w4thi, w4tlo, b4, recon, ND, NH, 8);

    // 4) distances + softmin
    dist_kernel<<<NB / 8, 512, 0, stream>>>(emb, reps, dist, wout);
}

// Round 7
// 183.494 us; speedup vs baseline: 1.0457x; 1.0457x over previous
//
#include <hip/hip_runtime.h>
#include <cstddef>

// Sizes (fixed per reference): B=8192, D=784, H=256, E=32, K=512
#define NB 8192
#define ND 784
#define NH 256
#define NE 32
#define NK 512
#define ALPHA_F 1000.0f

typedef _Float16 h8 __attribute__((ext_vector_type(8)));
typedef float f32x4 __attribute__((ext_vector_type(4)));

// ---------------------------------------------------------------------------
// Merged weight split+transpose: W [K][N] fp32 -> WT hi/lo [N][K] fp16.
// blocks 0..NH-1: W1 (K=ND); blocks NH..NH+ND-1: W4 (K=NH).
// w ~= hi + lo*2^-11; fp16 products exact in fp32 MFMA accumulator.
// ---------------------------------------------------------------------------
__global__ __launch_bounds__(256)
void splitw2_kernel(const float* __restrict__ W1, _Float16* __restrict__ w1thi,
                    _Float16* __restrict__ w1tlo,
                    const float* __restrict__ W4, _Float16* __restrict__ w4thi,
                    _Float16* __restrict__ w4tlo) {
    const int b = blockIdx.x;
    const float* W; _Float16 *hi, *lo; int K, N, n;
    if (b < NH) { W = W1; hi = w1thi; lo = w1tlo; K = ND; N = NH; n = b; }
    else        { W = W4; hi = w4thi; lo = w4tlo; K = NH; N = ND; n = b - NH; }
    for (int k = threadIdx.x; k < K; k += 256) {
        float w = W[(size_t)k * N + n];
        _Float16 hh = (_Float16)w;
        float r = w - (float)hh;
        hi[(size_t)n * K + k] = hh;
        lo[(size_t)n * K + k] = (_Float16)(r * 2048.0f);
    }
}

// ---------------------------------------------------------------------------
// MFMA split-fp16 GEMM v3: C[M,N] = op(A[M,K] @ W[K,N] + bias).
// W TRANSPOSED as hi/lo planes [N][K]. A fp32 [M][K] (SPLITA: conversion
// fused into LDS commit, off the critical path) or hi/lo fp16 planes.
// 256 threads (4 waves, 2x2 wave grid), BK=32, BN=64, BM=MT*32.
//   MT=2: wave tile 32x32 (gemm1);  MT=4: wave tile 64x32 (gemm4).
// DOUBLE-BUFFERED LDS, ONE barrier/step: compute on buf s&1 issues before
// the vmcnt wait for commit of s+1, so MFMA covers global latency;
// prefetch runs 2 steps ahead.  TERMS=4: hh+mid+ll; TERMS=3: drop ll.
// K ragged: 8-elem chunks zero-filled.  LDS row stride 40 halves: frag
// reads and staged writes are <=2-way bank-aliased (free).
// ---------------------------------------------------------------------------
template<int TERMS, bool RELU, bool SPLITA, int MT>
__global__ __launch_bounds__(256)
void mfma_gemm3(const float* __restrict__ Af32,
                const _Float16* __restrict__ Ahi_g,
                const _Float16* __restrict__ Alo_g,
                const _Float16* __restrict__ WThi,
                const _Float16* __restrict__ WTlo,
                const float* __restrict__ bias, float* __restrict__ C,
                int N, int K, int KS) {
    constexpr int BM  = MT * 32;
    constexpr int ACH = BM / 64;          // h8 chunks per thread per A plane

    __shared__ _Float16 sAhi[2][BM * 40];
    __shared__ _Float16 sAlo[2][BM * 40];
    __shared__ _Float16 sBhi[2][64 * 40];
    __shared__ _Float16 sBlo[2][64 * 40];

    const int tid = threadIdx.x;
    const int bm  = blockIdx.x * BM;
    const int bn  = blockIdx.y * 64;

    // staging map (conflict-clean): ACH=1: 4 thr/row, 8-elem chunks;
    //                               ACH=2: 2 thr/row, 16-elem chunks.
    const int arow = (ACH == 1) ? (tid >> 2) : (tid >> 1);
    const int ak   = (ACH == 1) ? ((tid & 3) * 8) : ((tid & 1) * 16);
    const int brow = tid >> 2;
    const int bk   = (tid & 3) * 8;

    const float*    pA32 = SPLITA ? Af32 + (size_t)(bm + arow) * K : nullptr;
    const _Float16* pAhi = SPLITA ? nullptr : Ahi_g + (size_t)(bm + arow) * K;
    const _Float16* pAlo = SPLITA ? nullptr : Alo_g + (size_t)(bm + arow) * K;
    int brow_g = bn + brow; if (brow_g > N - 1) brow_g = N - 1;  // N-edge tile
    const _Float16* pBhi = WThi + (size_t)brow_g * K;
    const _Float16* pBlo = WTlo + (size_t)brow_g * K;

    float araw[ACH * 8];                  // SPLITA raw fp32 prefetch
    h8 rahi[ACH], ralo[ACH];              // !SPLITA plane prefetch
    h8 rbhi, rblo;

    auto prefetch = [&](int s) {
        #pragma unroll
        for (int c = 0; c < ACH; ++c) {
            const int k = s * 32 + ak + c * 8;
            if (SPLITA) {
                if (k + 8 <= K) {
                    f32x4 v0 = *(const f32x4*)(pA32 + k);
                    f32x4 v1 = *(const f32x4*)(pA32 + k + 4);
                    #pragma unroll
                    for (int j = 0; j < 4; ++j) {
                        araw[c * 8 + j]     = v0[j];
                        araw[c * 8 + 4 + j] = v1[j];
                    }
                } else {
                    #pragma unroll
                    for (int j = 0; j < 8; ++j) araw[c * 8 + j] = 0.f;
                }
            } else {
                rahi[c] = (k + 8 <= K) ? *(const h8*)(pAhi + k) : (h8){};
                ralo[c] = (k + 8 <= K) ? *(const h8*)(pAlo + k) : (h8){};
            }
        }
        const int kb = s * 32 + bk;
        rbhi = (kb + 8 <= K) ? *(const h8*)(pBhi + kb) : (h8){};
        rblo = (kb + 8 <= K) ? *(const h8*)(pBlo + kb) : (h8){};
    };

    auto commit = [&](int buf) {
        #pragma unroll
        for (int c = 0; c < ACH; ++c) {
            h8 hi, lo;
            if (SPLITA) {
                #pragma unroll
                for (int j = 0; j < 8; ++j) {
                    float v = araw[c * 8 + j];
                    _Float16 hh = (_Float16)v;
                    hi[j] = hh;
                    lo[j] = (_Float16)((v - (float)hh) * 2048.0f);
                }
            } else { hi = rahi[c]; lo = ralo[c]; }
            *(h8*)&sAhi[buf][arow * 40 + ak + c * 8] = hi;
            *(h8*)&sAlo[buf][arow * 40 + ak + c * 8] = lo;
        }
        *(h8*)&sBhi[buf][brow * 40 + bk] = rbhi;
        *(h8*)&sBlo[buf][brow * 40 + bk] = rblo;
    };

    prefetch(0);
    commit(0);
    prefetch(1);
    __syncthreads();

    // wave mapping: 2x2 wave grid; wave tile (MT*16) x 32
    const int lane = tid & 63;
    const int wv   = tid >> 6;
    const int wm   = (wv >> 1) * (MT * 16);
    const int wn   = (wv & 1) * 32;
    const int li   = lane & 15;
    const int kq   = (lane >> 4) * 8;

    f32x4 acc0[MT][2] = {};
    f32x4 acc1[MT][2] = {};
    f32x4 acc2[MT][2] = {};

    for (int s = 0; s < KS; ++s) {
        const int buf = s & 1;
        h8 fahi[MT], falo[MT], fbhi[2], fblo[2];
        #pragma unroll
        for (int mt = 0; mt < MT; ++mt) {
            const int ao = (wm + mt * 16 + li) * 40 + kq;
            fahi[mt] = *(const h8*)&sAhi[buf][ao];
            falo[mt] = *(const h8*)&sAlo[buf][ao];
        }
        #pragma unroll
        for (int nt = 0; nt < 2; ++nt) {
            const int bo = (wn + nt * 16 + li) * 40 + kq;
            fbhi[nt] = *(const h8*)&sBhi[buf][bo];
            fblo[nt] = *(const h8*)&sBlo[buf][bo];
        }
        #pragma unroll
        for (int mt = 0; mt < MT; ++mt)
            #pragma unroll
            for (int nt = 0; nt < 2; ++nt) {
                acc0[mt][nt] = __builtin_amdgcn_mfma_f32_16x16x32_f16(
                    fahi[mt], fbhi[nt], acc0[mt][nt], 0, 0, 0);
                acc1[mt][nt] = __builtin_amdgcn_mfma_f32_16x16x32_f16(
                    fahi[mt], fblo[nt], acc1[mt][nt], 0, 0, 0);
                acc1[mt][nt] = __builtin_amdgcn_mfma_f32_16x16x32_f16(
                    falo[mt], fbhi[nt], acc1[mt][nt], 0, 0, 0);
                if (TERMS == 4)
                    acc2[mt][nt] = __builtin_amdgcn_mfma_f32_16x16x32_f16(
                        falo[mt], fblo[nt], acc2[mt][nt], 0, 0, 0);
            }
        if (s + 1 < KS) {
            commit((s + 1) & 1);                 // waits vmcnt (hidden by MFMA)
            if (s + 2 < KS) prefetch(s + 2);     // 2 steps ahead
        }
        __syncthreads();
    }

    const float c1 = 1.0f / 2048.0f;
    const float c2 = c1 * c1;
    const int quad = lane >> 4;
    #pragma unroll
    for (int nt = 0; nt < 2; ++nt) {
        const int n = bn + wn + nt * 16 + li;
        if (n < N) {
            const float bv = bias[n];
            #pragma unroll
            for (int mt = 0; mt < MT; ++mt) {
                #pragma unroll
                for (int r = 0; r < 4; ++r) {
                    const int m = bm + wm + mt * 16 + quad * 4 + r;
                    float v = acc0[mt][nt][r] + c1 * acc1[mt][nt][r];
                    if (TERMS == 4) v += c2 * acc2[mt][nt][r];
                    v += bv;
                    if (RELU) v = fmaxf(v, 0.f);
                    C[(size_t)m * N + n] = v;
                }
            }
        }
    }
}

// ---------------------------------------------------------------------------
// Fused: emb[B,32] = h@W2+b2 (fp32, precision-critical);
//        h2 = relu(emb@W3+b3) emitted as fp16 hi/lo planes for gemm4.
// Block = 16 rows, 256 threads, 512 blocks.
// ---------------------------------------------------------------------------
__global__ __launch_bounds__(256)
void mid_kernel(const float* __restrict__ h, const float* __restrict__ W2,
                const float* __restrict__ b2, const float* __restrict__ W3,
                const float* __restrict__ b3, float* __restrict__ emb,
                _Float16* __restrict__ h2hi, _Float16* __restrict__ h2lo) {
    __shared__ float es[16][32];
    const int tid = threadIdx.x;
    const int r0  = blockIdx.x * 16;

    #pragma unroll
    for (int half = 0; half < 2; ++half) {
        const int o   = tid + half * 256;
        const int row = o >> 5;
        const int col = o & 31;
        const float* hrow = h + (size_t)(r0 + row) * NH;
        float acc0 = 0.f, acc1 = 0.f;
        #pragma unroll 4
        for (int k = 0; k < NH; k += 4) {
            float4 hv = *(const float4*)(hrow + k);
            acc0 = fmaf(hv.x, W2[(k + 0) * NE + col], acc0);
            acc1 = fmaf(hv.y, W2[(k + 1) * NE + col], acc1);
            acc0 = fmaf(hv.z, W2[(k + 2) * NE + col], acc0);
            acc1 = fmaf(hv.w, W2[(k + 3) * NE + col], acc1);
        }
        float v = acc0 + acc1 + b2[col];
        es[row][col] = v;
        emb[(size_t)r0 * NE + o] = v;
    }
    __syncthreads();

    const int col = tid;
    float acc[16];
    #pragma unroll
    for (int r = 0; r < 16; ++r) acc[r] = 0.f;
    #pragma unroll
    for (int k = 0; k < NE; ++k) {
        float w = W3[k * NH + col];
        #pragma unroll
        for (int r = 0; r < 16; ++r) acc[r] = fmaf(es[r][k], w, acc[r]);
    }
    const float bb = b3[col];
    #pragma unroll
    for (int r = 0; r < 16; ++r) {
        float v = acc[r] + bb;
        v = v > 0.f ? v : 0.f;
        _Float16 hh = (_Float16)v;
        float rr = v - (float)hh;
        h2hi[(size_t)(r0 + r) * NH + col] = hh;
        h2lo[(size_t)(r0 + r) * NH + col] = (_Float16)(rr * 2048.0f);
    }
}

// ---------------------------------------------------------------------------
// Distances + stable softmin (v3, verified).
// 1024 blocks x 512 threads. Thread owns ONE cluster (tid) for 8 rows.
// Row reductions via padded LDS transpose + one 6-step shuffle.
// ---------------------------------------------------------------------------
__global__ __launch_bounds__(512, 4)
void dist_kernel(const float* __restrict__ emb, const float* __restrict__ reps,
                 float* __restrict__ dist, float* __restrict__ wout) {
    __shared__ float es[8][32];
    __shared__ float tr[8][520];
    __shared__ float rmin[8];
    __shared__ float rinv[8];

    const int tid = threadIdx.x;      // == cluster id
    const int r0  = blockIdx.x * 8;

    if (tid < 256) es[tid >> 5][tid & 31] = emb[(size_t)r0 * NE + tid];

    const float* rp = reps + (size_t)tid * NE;
    f32x4 rv[8];
    #pragma unroll
    for (int e4 = 0; e4 < 8; ++e4) rv[e4] = ((const f32x4*)rp)[e4];
    __syncthreads();

    float d[8];
    #pragma unroll
    for (int r = 0; r < 8; ++r) {
        float a = 0.f;
        #pragma unroll
        for (int e4 = 0; e4 < 8; ++e4) {
            f32x4 ev = *(const f32x4*)&es[r][e4 * 4];
            #pragma unroll
            for (int j = 0; j < 4; ++j) {
                float t = ev[j] - rv[e4][j];
                a = fmaf(t, t, a);
            }
        }
        d[r] = a;
    }

    const int lane = tid & 63;
    const int wv   = tid >> 6;

    #pragma unroll
    for (int r = 0; r < 8; ++r) tr[r][tid] = d[r];
    __syncthreads();
    {
        f32x4 a = *(const f32x4*)&tr[wv][lane * 8];
        f32x4 b = *(const f32x4*)&tr[wv][lane * 8 + 4];
        float m = fminf(fminf(fminf(a[0], a[1]), fminf(a[2], a[3])),
                        fminf(fminf(b[0], b[1]), fminf(b[2], b[3])));
        #pragma unroll
        for (int off = 32; off > 0; off >>= 1)
            m = fminf(m, __shfl_xor(m, off, 64));
        if (lane == 0) rmin[wv] = m;
    }
    __syncthreads();

    float e[8];
    #pragma unroll
    for (int r = 0; r < 8; ++r) {
        e[r] = expf(-ALPHA_F * (d[r] - rmin[r]));
        tr[r][tid] = e[r];
    }
    __syncthreads();
    {
        f32x4 a = *(const f32x4*)&tr[wv][lane * 8];
        f32x4 b = *(const f32x4*)&tr[wv][lane * 8 + 4];
        float s = ((a[0] + a[1]) + (a[2] + a[3])) +
                  ((b[0] + b[1]) + (b[2] + b[3]));
        #pragma unroll
        for (int off = 32; off > 0; off >>= 1)
            s += __shfl_xor(s, off, 64);
        if (lane == 0) rinv[wv] = 1.0f / s;
    }
    __syncthreads();

    #pragma unroll
    for (int r = 0; r < 8; ++r) {
        const size_t row = (size_t)(r0 + r);
        dist[row * NK + tid] = d[r];
        wout[row * NK + tid] = d[r] * (e[r] * rinv[r]);
    }
}

// ---------------------------------------------------------------------------
extern "C" void kernel_launch(void* const* d_in, const int* in_sizes, int n_in,
                              void* d_out, int out_size, void* d_ws, size_t ws_size,
                              hipStream_t stream) {
    const float* x    = (const float*)d_in[0];
    const float* reps = (const float*)d_in[1];
    const float* W1   = (const float*)d_in[2];
    const float* b1   = (const float*)d_in[3];
    const float* W2   = (const float*)d_in[4];
    const float* b2   = (const float*)d_in[5];
    const float* W3   = (const float*)d_in[6];
    const float* b3   = (const float*)d_in[7];
    const float* W4   = (const float*)d_in[8];
    const float* b4   = (const float*)d_in[9];

    float* out   = (float*)d_out;
    float* wout  = out;                                          // [8192,512]
    float* dist  = out + (size_t)NB * NK;                        // [8192,512]
    float* recon = out + (size_t)2 * NB * NK;                    // [8192,784]
    float* emb   = out + (size_t)2 * NB * NK + (size_t)NB * ND;  // [8192,32]

    // Scratch aliased into output regions not yet written at time of use:
    //  dist region (16 MiB): h fp32 (8 MiB) + h2 hi/lo planes (4+4 MiB);
    //    all dead before dist_kernel overwrites.
    //  wout region: W1T/W4T hi/lo planes (1.6 MiB); dead before dist_kernel.
    float*    h     = dist;
    _Float16* h2hi  = (_Float16*)(dist + (size_t)NB * NH);
    _Float16* h2lo  = h2hi + (size_t)NB * NH;
    _Float16* w1thi = (_Float16*)wout;
    _Float16* w1tlo = w1thi + (size_t)NH * ND;
    _Float16* w4thi = w1tlo + (size_t)NH * ND;
    _Float16* w4tlo = w4thi + (size_t)ND * NH;

    // 0) weight split+transpose (one launch for both W1 and W4)
    splitw2_kernel<<<NH + ND, 256, 0, stream>>>(W1, w1thi, w1tlo,
                                                W4, w4thi, w4tlo);

    // 1) h = relu(x @ W1 + b1)   M=8192 N=256 K=784, MT=2 (BM=64), KS=25
    mfma_gemm3<4, true, true, 2><<<dim3(128, 4), 256, 0, stream>>>(
        x, nullptr, nullptr, w1thi, w1tlo, b1, h, NH, ND, 25);

    // 2) emb + h2 (fp16 planes)
    mid_kernel<<<NB / 16, 256, 0, stream>>>(h, W2, b2, W3, b3, emb, h2hi, h2lo);

    // 3) recon = h2 @ W4 + b4    M=8192 N=784 K=256, MT=4 (BM=128), KS=8
    mfma_gemm3<3, false, false, 4><<<dim3(64, 13), 256, 0, stream>>>(
        nullptr, h2hi, h2lo, w4thi, w4tlo, b4, recon, ND, NH, 8);

    // 4) distances + softmin
    dist_kernel<<<NB / 8, 512, 0, stream>>>(emb, reps, dist, wout);
}